// Round 7
// baseline (2238.734 us; speedup 1.0000x reference)
//
#include <hip/hip_runtime.h>
#include <hip/hip_bf16.h>

#define NN 100000
#define NE 1600000
#define BNODES 98           // nodes per bucket
#define NB 1024             // buckets: 98*1024 = 100,352 >= NN
#define NBLKA 256           // blocks in hist/scatter
#define CHUNK 6250          // NE / NBLKA, exact

typedef unsigned short u16;
typedef unsigned int u32;
using frag  = __attribute__((ext_vector_type(8))) short;   // 8 bf16 = 4 VGPR
using f32x4 = __attribute__((ext_vector_type(4))) float;   // MFMA C/D

// ---------------- workspace layout (byte offsets), total 60,637,184 B ----------------
#define OFF_H     (0)                 // NBLKA*NB int = 1MB
#define OFF_BSUM  (1u << 20)          // NB int
#define OFF_BB    ((1u << 20) + 4096) // NB+1 int
#define OFF_REC   (2u << 20)          // NE u32 = 6.4MB (lives until after agg2)
#define OFF_WT1   (8704u << 10)       // 64KB bf16 packed
#define OFF_WT2   ((8704u << 10) + 65536u)
#define OFF_XB    (9u << 20)          // NN*128 bf16 = 25.6MB (becomes hb in-place)
#define OFF_AGGB  (35037184u)         // NN*128 bf16 = 25.6MB

// round-to-nearest-even f32 -> bf16 bits
__device__ __forceinline__ u16 f2bf(float f) {
    u32 u = __float_as_uint(f);
    u32 r = u + 0x7fffu + ((u >> 16) & 1u);
    return (u16)(r >> 16);
}

// per-block int64/int32 detection
__device__ __forceinline__ bool edges_are_i64(const void* edges) {
    const long long* e = (const long long*)edges;
    bool ok = true;
#pragma unroll
    for (int i = 0; i < 4; i++) {
        long long v = e[i];
        if (v < 0 || v >= NN) ok = false;
    }
    return ok;
}

// A1: per-block LDS histogram over NB buckets; H[blk*NB + b] (block-major)
__global__ __launch_bounds__(256) void hist_kernel(const void* edges, int* H) {
    __shared__ int h[NB];
    int tid = threadIdx.x, blk = blockIdx.x;
    for (int i = tid; i < NB; i += 256) h[i] = 0;
    __syncthreads();
    bool f = edges_are_i64(edges);
    int lo = blk * CHUNK, hi = lo + CHUNK;
    if (f) {
        const long long* dst = (const long long*)edges + NE;
        for (int i = lo + tid; i < hi; i += 256) atomicAdd(&h[(int)dst[i] / BNODES], 1);
    } else {
        const int* dst = (const int*)edges + NE;
        for (int i = lo + tid; i < hi; i += 256) atomicAdd(&h[dst[i] / BNODES], 1);
    }
    __syncthreads();
    for (int i = tid; i < NB; i += 256) H[blk * NB + i] = h[i];
}

// A2a: wave-per-bucket exclusive scan over the 256 block entries; bsum[b] = total
__global__ __launch_bounds__(256) void scan_kernel(int* H, int* bsum) {
    int tid = threadIdx.x;
    int lane = tid & 63;
    int b = blockIdx.x * 4 + (tid >> 6);
    int v0 = H[(lane * 4 + 0) * NB + b];
    int v1 = H[(lane * 4 + 1) * NB + b];
    int v2 = H[(lane * 4 + 2) * NB + b];
    int v3 = H[(lane * 4 + 3) * NB + b];
    int t = v0 + v1 + v2 + v3;
    int sc = t;
#pragma unroll
    for (int off = 1; off < 64; off <<= 1) {
        int v = __shfl_up(sc, off, 64);
        if (lane >= off) sc += v;
    }
    int excl = sc - t;
    H[(lane * 4 + 0) * NB + b] = excl;
    H[(lane * 4 + 1) * NB + b] = excl + v0;
    H[(lane * 4 + 2) * NB + b] = excl + v0 + v1;
    H[(lane * 4 + 3) * NB + b] = excl + v0 + v1 + v2;
    if (lane == 63) bsum[b] = sc;
}

// A2b: exclusive prefix over NB bucket totals -> bb[]
__global__ void bb_kernel(const int* bsum, int* bb) {
    __shared__ int sc[NB];
    int tid = threadIdx.x;  // 1024 threads
    int s = bsum[tid];
    sc[tid] = s;
    __syncthreads();
    for (int off = 1; off < NB; off <<= 1) {
        int v = (tid >= off) ? sc[tid - off] : 0;
        __syncthreads();
        sc[tid] += v;
        __syncthreads();
    }
    bb[tid] = sc[tid] - s;
    if (tid == NB - 1) bb[NB] = sc[NB - 1];
}

// A3: scatter packed records (dst_local<<17 | src) into exact per-(block,bucket) regions
__global__ __launch_bounds__(256) void scatter_kernel(const void* edges, const int* H,
                                                      const int* bb, u32* rec) {
    __shared__ int cur[NB];
    int tid = threadIdx.x, blk = blockIdx.x;
    for (int i = tid; i < NB; i += 256) cur[i] = bb[i] + H[blk * NB + i];
    __syncthreads();
    bool f = edges_are_i64(edges);
    int lo = blk * CHUNK, hi = lo + CHUNK;
    if (f) {
        const long long* e = (const long long*)edges;
        for (int i = lo + tid; i < hi; i += 256) {
            int d = (int)e[NE + i], s = (int)e[i];
            int b = d / BNODES;
            int p = atomicAdd(&cur[b], 1);
            rec[p] = ((u32)(d - b * BNODES) << 17) | (u32)s;
        }
    } else {
        const int* e = (const int*)edges;
        for (int i = lo + tid; i < hi; i += 256) {
            int d = e[NE + i], s = e[i];
            int b = d / BNODES;
            int p = atomicAdd(&cur[b], 1);
            rec[p] = ((u32)(d - b * BNODES) << 17) | (u32)s;
        }
    }
}

// B: edge-parallel mean-aggregation per bucket, LDS f32 accumulator.
// Plane layout: x at facc[row*128 + p], y at facc[row*128 + 64 + p] (p = lane)
// -> ds_add_f32 hits 2 lanes/bank = conflict-free.
__global__ __launch_bounds__(512) void agg_rec_kernel(const u16* __restrict__ feat,
                                                      const u32* __restrict__ rec,
                                                      const int* __restrict__ bb,
                                                      u16* __restrict__ aggb) {
    __shared__ float facc[BNODES * 128];
    __shared__ int ndeg[BNODES];
    int tid = threadIdx.x;
    int lane = tid & 63;
    int w = tid >> 6;       // 8 waves
    int b = blockIdx.x;

    for (int i = tid; i < BNODES * 32; i += 512) *(float4*)&facc[i * 4] = make_float4(0, 0, 0, 0);
    if (tid < BNODES) ndeg[tid] = 0;
    __syncthreads();

    int base = bb[b], end = bb[b + 1];
    int nrec = end - base;
    int n4 = nrec & ~31;

    for (int i = base + w * 4; i < base + n4; i += 32) {
        u32 r0 = rec[i], r1 = rec[i + 1], r2 = rec[i + 2], r3 = rec[i + 3];
        u32 v0 = *(const u32*)(feat + (size_t)(r0 & 0x1FFFFu) * 128 + lane * 2);
        u32 v1 = *(const u32*)(feat + (size_t)(r1 & 0x1FFFFu) * 128 + lane * 2);
        u32 v2 = *(const u32*)(feat + (size_t)(r2 & 0x1FFFFu) * 128 + lane * 2);
        u32 v3 = *(const u32*)(feat + (size_t)(r3 & 0x1FFFFu) * 128 + lane * 2);
        int d0 = r0 >> 17, d1 = r1 >> 17, d2 = r2 >> 17, d3 = r3 >> 17;
        atomicAdd(&facc[d0 * 128 + lane], __uint_as_float(v0 << 16));
        atomicAdd(&facc[d0 * 128 + 64 + lane], __uint_as_float(v0 & 0xffff0000u));
        atomicAdd(&facc[d1 * 128 + lane], __uint_as_float(v1 << 16));
        atomicAdd(&facc[d1 * 128 + 64 + lane], __uint_as_float(v1 & 0xffff0000u));
        atomicAdd(&facc[d2 * 128 + lane], __uint_as_float(v2 << 16));
        atomicAdd(&facc[d2 * 128 + 64 + lane], __uint_as_float(v2 & 0xffff0000u));
        atomicAdd(&facc[d3 * 128 + lane], __uint_as_float(v3 << 16));
        atomicAdd(&facc[d3 * 128 + 64 + lane], __uint_as_float(v3 & 0xffff0000u));
        if (lane == 0) {
            atomicAdd(&ndeg[d0], 1); atomicAdd(&ndeg[d1], 1);
            atomicAdd(&ndeg[d2], 1); atomicAdd(&ndeg[d3], 1);
        }
    }
    for (int i = base + n4 + w; i < end; i += 8) {
        u32 r = rec[i];
        u32 v = *(const u32*)(feat + (size_t)(r & 0x1FFFFu) * 128 + lane * 2);
        int d = r >> 17;
        atomicAdd(&facc[d * 128 + lane], __uint_as_float(v << 16));
        atomicAdd(&facc[d * 128 + 64 + lane], __uint_as_float(v & 0xffff0000u));
        if (lane == 0) atomicAdd(&ndeg[d], 1);
    }
    __syncthreads();

    for (int idx = tid; idx < BNODES * 64; idx += 512) {
        int row = idx >> 6, p = idx & 63;
        int node = b * BNODES + row;
        if (node >= NN) continue;
        int deg = ndeg[row];
        float inv = (deg > 0) ? 1.0f / (float)deg : 0.0f;
        float fx = facc[row * 128 + p] * inv;
        float fy = facc[row * 128 + 64 + p] * inv;
        u32 pk = (u32)f2bf(fx) | ((u32)f2bf(fy) << 16);
        *(u32*)(aggb + (size_t)node * 128 + p * 2) = pk;
    }
}

// both layers' weights in one launch
__global__ void wtprep_kernel(const float* Wl1, const float* Wr1,
                              const float* Wl2, const float* Wr2, u16* Wst1, u16* Wst2) {
    int gid = blockIdx.x * 256 + threadIdx.x;
    int idx = gid & (32 * 128 * 8 - 1);
    const float* Wl = (gid < 32768) ? Wl1 : Wl2;
    const float* Wr = (gid < 32768) ? Wr1 : Wr2;
    u16* Wst = (gid < 32768) ? Wst1 : Wst2;
    int kb = idx >> 10, col = (idx >> 3) & 127, i = idx & 7;
    int k = kb * 8 + i;
    float v = (k < 128) ? Wl[col * 128 + k] : Wr[col * 128 + (k - 128)];
    Wst[idx] = f2bf(v);
}

// f32 x -> bf16 xb, 8 elems/thread
__global__ void cvt_kernel(const float* x, u16* xb) {
    size_t base = ((size_t)blockIdx.x * 256 + threadIdx.x) * 8;
    if (base >= (size_t)NN * 128) return;
    float4 v0 = *(const float4*)(x + base);
    float4 v1 = *(const float4*)(x + base + 4);
    uint4 w;
    w.x = (u32)f2bf(v0.x) | ((u32)f2bf(v0.y) << 16);
    w.y = (u32)f2bf(v0.z) | ((u32)f2bf(v0.w) << 16);
    w.z = (u32)f2bf(v1.x) | ((u32)f2bf(v1.y) << 16);
    w.w = (u32)f2bf(v1.z) | ((u32)f2bf(v1.w) << 16);
    *(uint4*)(xb + base) = w;
}

// MFMA GEMM: out[n,o] = sum_k [A||B][n,k] * W[k,o] + bias[o], K=256.
__global__ __launch_bounds__(256) void lin_kernel(const u16* __restrict__ Abuf,
                                                  const u16* __restrict__ Bbuf,
                                                  const u16* __restrict__ Wst,
                                                  const float* __restrict__ bias,
                                                  float* outF, u16* outH, int relu) {
    __shared__ u16 As[128][136];   // +8 pad: rows 4 banks apart
    __shared__ u16 Ws[16384];      // [16 kb][128 col][8 k] bf16, chunk-local

    int tid = threadIdx.x;
    int lane = tid & 63;
    int wid = tid >> 6;
    int wr = wid >> 1, wc = wid & 1;
    int nb = blockIdx.x * 128;
    int l15 = lane & 15, l4 = lane >> 4;

    f32x4 acc[4][4];
#pragma unroll
    for (int i = 0; i < 4; i++)
#pragma unroll
        for (int j = 0; j < 4; j++) acc[i][j] = (f32x4){0.f, 0.f, 0.f, 0.f};

    for (int c = 0; c < 2; c++) {
        const u16* Base = c ? Bbuf : Abuf;
        __syncthreads();

#pragma unroll
        for (int it = 0; it < 8; it++) {
            int idx = it * 256 + tid;
            int row = idx >> 4, c16 = idx & 15;
            float4 v = make_float4(0.f, 0.f, 0.f, 0.f);
            if (nb + row < NN)
                v = *(const float4*)(Base + (size_t)(nb + row) * 128 + c16 * 8);
            *(float4*)&As[row][c16 * 8] = v;
        }
        const u16* wsrc = Wst + c * 16384;
#pragma unroll
        for (int it = 0; it < 8; it++) {
            int idx = it * 256 + tid;
            *(float4*)&Ws[idx * 8] = *(const float4*)(wsrc + idx * 8);
        }
        __syncthreads();

#pragma unroll
        for (int kk = 0; kk < 4; kk++) {
            frag a[4], bfr[4];
#pragma unroll
            for (int i = 0; i < 4; i++)
                a[i] = *(const frag*)&As[wr * 64 + i * 16 + l15][kk * 32 + l4 * 8];
#pragma unroll
            for (int j = 0; j < 4; j++)
                bfr[j] = *(const frag*)&Ws[((kk * 4 + l4) * 128 + wc * 64 + j * 16 + l15) * 8];
#pragma unroll
            for (int i = 0; i < 4; i++)
#pragma unroll
                for (int j = 0; j < 4; j++)
                    acc[i][j] = __builtin_amdgcn_mfma_f32_16x16x32_bf16(a[i], bfr[j], acc[i][j], 0, 0, 0);
        }
    }

    // epilogue: C/D layout col = lane&15, row = (lane>>4)*4 + reg
#pragma unroll
    for (int j = 0; j < 4; j++) {
        int col = wc * 64 + j * 16 + l15;
        float bv = bias[col];
#pragma unroll
        for (int i = 0; i < 4; i++) {
#pragma unroll
            for (int r = 0; r < 4; r++) {
                int node = nb + wr * 64 + i * 16 + l4 * 4 + r;
                if (node >= NN) continue;
                float v = acc[i][j][r] + bv;
                if (relu) {
                    v = fmaxf(v, 0.f);
                    outH[(size_t)node * 128 + col] = f2bf(v);
                } else {
                    outF[(size_t)node * 128 + col] = v;
                }
            }
        }
    }
}

extern "C" void kernel_launch(void* const* d_in, const int* in_sizes, int n_in,
                              void* d_out, int out_size, void* d_ws, size_t ws_size,
                              hipStream_t stream) {
    const float* x    = (const float*)d_in[0];
    const void* edges = d_in[1];
    const float* Wl1  = (const float*)d_in[2];
    const float* Wr1  = (const float*)d_in[3];
    const float* b1   = (const float*)d_in[4];
    const float* Wl2  = (const float*)d_in[5];
    const float* Wr2  = (const float*)d_in[6];
    const float* b2   = (const float*)d_in[7];
    float* out = (float*)d_out;

    char* ws = (char*)d_ws;
    int* H      = (int*)(ws + OFF_H);
    int* bsum   = (int*)(ws + OFF_BSUM);
    int* bb     = (int*)(ws + OFF_BB);
    u32* rec    = (u32*)(ws + OFF_REC);
    u16* Wst1   = (u16*)(ws + OFF_WT1);
    u16* Wst2   = (u16*)(ws + OFF_WT2);
    u16* xb     = (u16*)(ws + OFF_XB);    // becomes hb after lin1 (in-place)
    u16* aggb   = (u16*)(ws + OFF_AGGB);

    // bucket-sorted edge records: zero global atomics
    hist_kernel<<<NBLKA, 256, 0, stream>>>(edges, H);
    scan_kernel<<<NB / 4, 256, 0, stream>>>(H, bsum);
    bb_kernel<<<1, NB, 0, stream>>>(bsum, bb);
    scatter_kernel<<<NBLKA, 256, 0, stream>>>(edges, H, bb, rec);

    wtprep_kernel<<<256, 256, 0, stream>>>(Wl1, Wr1, Wl2, Wr2, Wst1, Wst2);
    cvt_kernel<<<6250, 256, 0, stream>>>(x, xb);

    int lgrid = (NN + 127) / 128;  // 782

    // layer 1: agg1 = mean-gather(xb); h = relu(lin(agg1, xb)) -> bf16 in-place into xb
    agg_rec_kernel<<<NB, 512, 0, stream>>>(xb, rec, bb, aggb);
    lin_kernel<<<lgrid, 256, 0, stream>>>(aggb, xb, Wst1, b1, nullptr, xb, 1);

    // layer 2: agg2 = mean-gather(hb); out = lin(agg2, hb) -> f32 d_out
    agg_rec_kernel<<<NB, 512, 0, stream>>>(xb, rec, bb, aggb);
    lin_kernel<<<lgrid, 256, 0, stream>>>(aggb, xb, Wst2, b2, out, nullptr, 0);
}

// Round 8
// 295.760 us; speedup vs baseline: 7.5694x; 7.5694x over previous
//
#include <hip/hip_runtime.h>
#include <hip/hip_bf16.h>

#define NN 100000
#define NE 1600000
#define BNODES 196          // nodes per bucket
#define NB 511              // ceil(NN/BNODES)
#define NBLKA 256           // blocks in hist/scatter
#define CHUNK 6250          // NE / NBLKA, exact

typedef unsigned short u16;
typedef unsigned int u32;
using frag  = __attribute__((ext_vector_type(8))) short;   // 8 bf16 = 4 VGPR
using f32x4 = __attribute__((ext_vector_type(4))) float;   // MFMA C/D

// ---------------- workspace layout (byte offsets), total 60,637,184 B ----------------
#define OFF_CNT   (0)                 // NN int
#define OFF_OFFS  (512u << 10)        // NN int
#define OFF_BB    (1u << 20)          // NB+2 int
#define OFF_H     (1310720u)          // NBLKA*512 int = 512KB (dead after A3)
#define OFF_CSR   (2u << 20)          // NE int
#define OFF_WT1   (8704u << 10)       // 32KB bf16 packed
#define OFF_WT2   ((8704u << 10) + 65536u)
#define OFF_XB    (9u << 20)          // NN*128 bf16 = 25.6MB (becomes hb in-place)
#define OFF_AGGB  (35037184u)         // NN*128 bf16 = 25.6MB
#define OFF_REC   (54237184u)         // NE u32 = 6.4MB, overlaps aggb tail (dead by agg)

// round-to-nearest-even f32 -> bf16 bits
__device__ __forceinline__ u16 f2bf(float f) {
    u32 u = __float_as_uint(f);
    u32 r = u + 0x7fffu + ((u >> 16) & 1u);
    return (u16)(r >> 16);
}

// per-block int64/int32 detection
__device__ __forceinline__ bool edges_are_i64(const void* edges) {
    const long long* e = (const long long*)edges;
    bool ok = true;
#pragma unroll
    for (int i = 0; i < 4; i++) {
        long long v = e[i];
        if (v < 0 || v >= NN) ok = false;
    }
    return ok;
}

// A1: per-block LDS histogram over buckets (LDS int atomics only)
__global__ __launch_bounds__(256) void hist_kernel(const void* edges, int* H) {
    __shared__ int h[512];
    int tid = threadIdx.x, blk = blockIdx.x;
    for (int i = tid; i < 512; i += 256) h[i] = 0;
    __syncthreads();
    bool f = edges_are_i64(edges);
    int lo = blk * CHUNK, hi = lo + CHUNK;
    if (f) {
        const long long* dst = (const long long*)edges + NE;
        for (int i = lo + tid; i < hi; i += 256) atomicAdd(&h[(int)dst[i] / BNODES], 1);
    } else {
        const int* dst = (const int*)edges + NE;
        for (int i = lo + tid; i < hi; i += 256) atomicAdd(&h[dst[i] / BNODES], 1);
    }
    __syncthreads();
    for (int i = tid; i < 512; i += 256) H[blk * 512 + i] = h[i];
}

// A2: H[blk][b] -> exclusive prefix over blk, + bucket bases bb[]; rebase H to global indices
__global__ void scan_kernel(int* H, int* bb) {
    __shared__ int sc[512];
    int b = threadIdx.x;  // 512 threads
    int s = 0;
    for (int blk = 0; blk < NBLKA; blk++) {
        int v = H[blk * 512 + b];
        H[blk * 512 + b] = s;
        s += v;
    }
    sc[b] = s;
    __syncthreads();
    for (int off = 1; off < 512; off <<= 1) {
        int v = (b >= off) ? sc[b - off] : 0;
        __syncthreads();
        sc[b] += v;
        __syncthreads();
    }
    bb[b] = sc[b] - s;          // exclusive bucket base
    if (b == 511) bb[512] = sc[511];
    __syncthreads();
    int base = bb[b];
    for (int blk = 0; blk < NBLKA; blk++) H[blk * 512 + b] += base;
}

// A3: scatter packed records (dst_local<<17 | src) into exact per-(block,bucket) regions
__global__ __launch_bounds__(256) void scatter_kernel(const void* edges, const int* H, u32* rec) {
    __shared__ int cur[512];
    int tid = threadIdx.x, blk = blockIdx.x;
    for (int i = tid; i < 512; i += 256) cur[i] = H[blk * 512 + i];
    __syncthreads();
    bool f = edges_are_i64(edges);
    int lo = blk * CHUNK, hi = lo + CHUNK;
    if (f) {
        const long long* e = (const long long*)edges;
        for (int i = lo + tid; i < hi; i += 256) {
            int d = (int)e[NE + i], s = (int)e[i];
            int b = d / BNODES;
            int p = atomicAdd(&cur[b], 1);
            rec[p] = ((u32)(d - b * BNODES) << 17) | (u32)s;
        }
    } else {
        const int* e = (const int*)edges;
        for (int i = lo + tid; i < hi; i += 256) {
            int d = e[NE + i], s = e[i];
            int b = d / BNODES;
            int p = atomicAdd(&cur[b], 1);
            rec[p] = ((u32)(d - b * BNODES) << 17) | (u32)s;
        }
    }
}

// B: per-bucket: LDS hist -> prefix -> cnt/offsets (no global atomics) -> csr scatter
__global__ __launch_bounds__(256) void bucket_csr_kernel(const u32* rec, const int* bb,
                                                         int* cnt, int* offsets, int* csr) {
    __shared__ int hcnt[200], hpre[200], hcur[200];
    int b = blockIdx.x, tid = threadIdx.x;
    int base = bb[b], total = bb[b + 1] - base;
    for (int i = tid; i < BNODES; i += 256) hcnt[i] = 0;
    __syncthreads();
    for (int i = tid; i < total; i += 256) atomicAdd(&hcnt[rec[base + i] >> 17], 1);
    __syncthreads();
    if (tid < 64) {  // wave 0: exclusive prefix over 196 counters (49 lanes x 4)
        int l = tid;
        int s0 = 0, s1 = 0, s2 = 0, s3 = 0;
        if (l < 49) {
            s0 = hcnt[l * 4]; s1 = hcnt[l * 4 + 1]; s2 = hcnt[l * 4 + 2]; s3 = hcnt[l * 4 + 3];
        }
        int t0 = s0, t1 = t0 + s1, t2 = t1 + s2, t3 = t2 + s3;
        int sc = t3;
#pragma unroll
        for (int off = 1; off < 64; off <<= 1) {
            int v = __shfl_up(sc, off, 64);
            if (l >= off) sc += v;
        }
        int lbase = sc - t3;
        if (l < 49) {
            hpre[l * 4] = lbase;      hpre[l * 4 + 1] = lbase + t0;
            hpre[l * 4 + 2] = lbase + t1; hpre[l * 4 + 3] = lbase + t2;
        }
    }
    __syncthreads();
    int node0 = b * BNODES;
    for (int i = tid; i < BNODES; i += 256) {
        int n = node0 + i;
        if (n < NN) { cnt[n] = hcnt[i]; offsets[n] = base + hpre[i]; }
    }
    for (int i = tid; i < BNODES; i += 256) hcur[i] = hpre[i];
    __syncthreads();
    for (int i = tid; i < total; i += 256) {
        u32 r = rec[base + i];
        int p = atomicAdd(&hcur[r >> 17], 1);
        csr[base + p] = (int)(r & 0x1FFFFu);
    }
}

// both layers' weights in one launch
__global__ void wtprep_kernel(const float* Wl1, const float* Wr1,
                              const float* Wl2, const float* Wr2, u16* Wst1, u16* Wst2) {
    int gid = blockIdx.x * 256 + threadIdx.x;
    int idx = gid & (32 * 128 * 8 - 1);
    const float* Wl = (gid < 32768) ? Wl1 : Wl2;
    const float* Wr = (gid < 32768) ? Wr1 : Wr2;
    u16* Wst = (gid < 32768) ? Wst1 : Wst2;
    int kb = idx >> 10, col = (idx >> 3) & 127, i = idx & 7;
    int k = kb * 8 + i;
    float v = (k < 128) ? Wl[col * 128 + k] : Wr[col * 128 + (k - 128)];
    Wst[idx] = f2bf(v);
}

// f32 x -> bf16 xb, 8 elems/thread
__global__ void cvt_kernel(const float* x, u16* xb) {
    size_t base = ((size_t)blockIdx.x * 256 + threadIdx.x) * 8;
    if (base >= (size_t)NN * 128) return;
    float4 v0 = *(const float4*)(x + base);
    float4 v1 = *(const float4*)(x + base + 4);
    uint4 w;
    w.x = (u32)f2bf(v0.x) | ((u32)f2bf(v0.y) << 16);
    w.y = (u32)f2bf(v0.z) | ((u32)f2bf(v0.w) << 16);
    w.z = (u32)f2bf(v1.x) | ((u32)f2bf(v1.y) << 16);
    w.w = (u32)f2bf(v1.z) | ((u32)f2bf(v1.w) << 16);
    *(uint4*)(xb + base) = w;
}

// 4 nodes per wave: slot = lane>>4, 16 lanes x 16B (uint4) per 256B row.
// 4 independent chains/wave, 4KB in flight at unroll 4. No atomics.
__global__ __launch_bounds__(256) void agg_kernel(const u16* __restrict__ feat,
                                                  const int* __restrict__ csr,
                                                  const int* __restrict__ offsets,
                                                  const int* __restrict__ cnt,
                                                  u16* __restrict__ aggb) {
    int tid = threadIdx.x;
    int lane = tid & 63;
    int wv = tid >> 6;            // wave in block (4)
    int slot = lane >> 4;         // node slot 0..3
    int c16 = lane & 15;          // 16B chunk within row
    int node = blockIdx.x * 16 + wv * 4 + slot;
    bool valid = node < NN;
    int beg = valid ? offsets[node] : 0;
    int deg = valid ? cnt[node] : 0;

    // max deg across the wave's 4 slots (loop bound is wave-uniform)
    int md = deg;
    md = max(md, __shfl_xor(md, 16, 64));
    md = max(md, __shfl_xor(md, 32, 64));

    float acc[8];
#pragma unroll
    for (int q = 0; q < 8; q++) acc[q] = 0.f;

    for (int j = 0; j < md; j += 4) {
#pragma unroll
        for (int k = 0; k < 4; k++) {
            if (j + k < deg) {
                int s = csr[beg + j + k];
                uint4 v = *(const uint4*)(feat + (size_t)s * 128 + c16 * 8);
                acc[0] += __uint_as_float(v.x << 16);
                acc[1] += __uint_as_float(v.x & 0xffff0000u);
                acc[2] += __uint_as_float(v.y << 16);
                acc[3] += __uint_as_float(v.y & 0xffff0000u);
                acc[4] += __uint_as_float(v.z << 16);
                acc[5] += __uint_as_float(v.z & 0xffff0000u);
                acc[6] += __uint_as_float(v.w << 16);
                acc[7] += __uint_as_float(v.w & 0xffff0000u);
            }
        }
    }

    if (valid) {
        float inv = (deg > 0) ? 1.0f / (float)deg : 0.0f;
        uint4 w;
        w.x = (u32)f2bf(acc[0] * inv) | ((u32)f2bf(acc[1] * inv) << 16);
        w.y = (u32)f2bf(acc[2] * inv) | ((u32)f2bf(acc[3] * inv) << 16);
        w.z = (u32)f2bf(acc[4] * inv) | ((u32)f2bf(acc[5] * inv) << 16);
        w.w = (u32)f2bf(acc[6] * inv) | ((u32)f2bf(acc[7] * inv) << 16);
        *(uint4*)(aggb + (size_t)node * 128 + c16 * 8) = w;
    }
}

// MFMA GEMM: out[n,o] = sum_k [A||B][n,k] * W[k,o] + bias[o], K=256.
__global__ __launch_bounds__(256) void lin_kernel(const u16* __restrict__ Abuf,
                                                  const u16* __restrict__ Bbuf,
                                                  const u16* __restrict__ Wst,
                                                  const float* __restrict__ bias,
                                                  float* outF, u16* outH, int relu) {
    __shared__ u16 As[128][136];   // +8 pad: rows 4 banks apart
    __shared__ u16 Ws[16384];      // [16 kb][128 col][8 k] bf16, chunk-local

    int tid = threadIdx.x;
    int lane = tid & 63;
    int wid = tid >> 6;
    int wr = wid >> 1, wc = wid & 1;
    int nb = blockIdx.x * 128;
    int l15 = lane & 15, l4 = lane >> 4;

    f32x4 acc[4][4];
#pragma unroll
    for (int i = 0; i < 4; i++)
#pragma unroll
        for (int j = 0; j < 4; j++) acc[i][j] = (f32x4){0.f, 0.f, 0.f, 0.f};

    for (int c = 0; c < 2; c++) {
        const u16* Base = c ? Bbuf : Abuf;
        __syncthreads();

#pragma unroll
        for (int it = 0; it < 8; it++) {
            int idx = it * 256 + tid;
            int row = idx >> 4, c16 = idx & 15;
            float4 v = make_float4(0.f, 0.f, 0.f, 0.f);
            if (nb + row < NN)
                v = *(const float4*)(Base + (size_t)(nb + row) * 128 + c16 * 8);
            *(float4*)&As[row][c16 * 8] = v;
        }
        const u16* wsrc = Wst + c * 16384;
#pragma unroll
        for (int it = 0; it < 8; it++) {
            int idx = it * 256 + tid;
            *(float4*)&Ws[idx * 8] = *(const float4*)(wsrc + idx * 8);
        }
        __syncthreads();

#pragma unroll
        for (int kk = 0; kk < 4; kk++) {
            frag a[4], bfr[4];
#pragma unroll
            for (int i = 0; i < 4; i++)
                a[i] = *(const frag*)&As[wr * 64 + i * 16 + l15][kk * 32 + l4 * 8];
#pragma unroll
            for (int j = 0; j < 4; j++)
                bfr[j] = *(const frag*)&Ws[((kk * 4 + l4) * 128 + wc * 64 + j * 16 + l15) * 8];
#pragma unroll
            for (int i = 0; i < 4; i++)
#pragma unroll
                for (int j = 0; j < 4; j++)
                    acc[i][j] = __builtin_amdgcn_mfma_f32_16x16x32_bf16(a[i], bfr[j], acc[i][j], 0, 0, 0);
        }
    }

    // epilogue: C/D layout col = lane&15, row = (lane>>4)*4 + reg
#pragma unroll
    for (int j = 0; j < 4; j++) {
        int col = wc * 64 + j * 16 + l15;
        float bv = bias[col];
#pragma unroll
        for (int i = 0; i < 4; i++) {
#pragma unroll
            for (int r = 0; r < 4; r++) {
                int node = nb + wr * 64 + i * 16 + l4 * 4 + r;
                if (node >= NN) continue;
                float v = acc[i][j][r] + bv;
                if (relu) {
                    v = fmaxf(v, 0.f);
                    outH[(size_t)node * 128 + col] = f2bf(v);
                } else {
                    outF[(size_t)node * 128 + col] = v;
                }
            }
        }
    }
}

extern "C" void kernel_launch(void* const* d_in, const int* in_sizes, int n_in,
                              void* d_out, int out_size, void* d_ws, size_t ws_size,
                              hipStream_t stream) {
    const float* x    = (const float*)d_in[0];
    const void* edges = d_in[1];
    const float* Wl1  = (const float*)d_in[2];
    const float* Wr1  = (const float*)d_in[3];
    const float* b1   = (const float*)d_in[4];
    const float* Wl2  = (const float*)d_in[5];
    const float* Wr2  = (const float*)d_in[6];
    const float* b2   = (const float*)d_in[7];
    float* out = (float*)d_out;

    char* ws = (char*)d_ws;
    int* cnt     = (int*)(ws + OFF_CNT);
    int* offsets = (int*)(ws + OFF_OFFS);
    int* bb      = (int*)(ws + OFF_BB);
    int* H       = (int*)(ws + OFF_H);
    int* csr     = (int*)(ws + OFF_CSR);
    u16* Wst1    = (u16*)(ws + OFF_WT1);
    u16* Wst2    = (u16*)(ws + OFF_WT2);
    u16* xb      = (u16*)(ws + OFF_XB);    // becomes hb after lin1 (in-place)
    u16* aggb    = (u16*)(ws + OFF_AGGB);
    u32* rec     = (u32*)(ws + OFF_REC);   // overlaps aggb tail; dead before agg1

    // CSR build: zero global atomics
    hist_kernel<<<NBLKA, 256, 0, stream>>>(edges, H);
    scan_kernel<<<1, 512, 0, stream>>>(H, bb);
    scatter_kernel<<<NBLKA, 256, 0, stream>>>(edges, H, rec);
    bucket_csr_kernel<<<NB, 256, 0, stream>>>(rec, bb, cnt, offsets, csr);

    wtprep_kernel<<<256, 256, 0, stream>>>(Wl1, Wr1, Wl2, Wr2, Wst1, Wst2);
    cvt_kernel<<<6250, 256, 0, stream>>>(x, xb);

    int lgrid = (NN + 127) / 128;  // 782
    int agrid = (NN + 15) / 16;    // 6250

    // layer 1: agg1 = mean-gather(xb); h = relu(lin(agg1, xb)) -> bf16 in-place into xb
    agg_kernel<<<agrid, 256, 0, stream>>>(xb, csr, offsets, cnt, aggb);
    lin_kernel<<<lgrid, 256, 0, stream>>>(aggb, xb, Wst1, b1, nullptr, xb, 1);

    // layer 2: agg2 = mean-gather(hb); out = lin(agg2, hb) -> f32 d_out
    agg_kernel<<<agrid, 256, 0, stream>>>(xb, csr, offsets, cnt, aggb);
    lin_kernel<<<lgrid, 256, 0, stream>>>(aggb, xb, Wst2, b2, out, nullptr, 0);
}